// Round 10
// baseline (1105.195 us; speedup 1.0000x reference)
//
#include <hip/hip_runtime.h>
#include <hip/hip_bf16.h>
#include <stdint.h>

#define N_NODES 50000
#define N_EDGES 400000
#define F_IN 256
#define HID 1024
#define F_MID 512
#define F_OUT 10

typedef _Float16 f16;
typedef _Float16 f16x4 __attribute__((ext_vector_type(4)));
typedef _Float16 f16x8 __attribute__((ext_vector_type(8)));
typedef float f32x4 __attribute__((ext_vector_type(4)));

__device__ static inline void async_load16(const void* g, void* l) {
    __builtin_amdgcn_global_load_lds(
        (const __attribute__((address_space(1))) unsigned int*)(uintptr_t)g,
        (__attribute__((address_space(3))) unsigned int*)(uintptr_t)l, 16, 0, 0);
}

// ---------------- utility ----------------
__global__ __launch_bounds__(256) void zero_i32(int* __restrict__ p, int n) {
    int i = blockIdx.x * 256 + threadIdx.x;
    if (i < n) p[i] = 0;
}

__global__ __launch_bounds__(256) void probe_kernel(float* __restrict__ out, int n, float val) {
    int i = blockIdx.x * 256 + threadIdx.x;
    if (i < n) out[i] = (i == 0) ? val : 0.f;
}

// ---------------- CSR build ----------------
__global__ __launch_bounds__(256) void hist_kernel(const int* __restrict__ dst, int* __restrict__ rowptr) {
    int e = blockIdx.x * 256 + threadIdx.x;
    if (e < N_EDGES) atomicAdd(&rowptr[dst[e] + 1], 1);
}

__global__ __launch_bounds__(256) void scan1_kernel(int* __restrict__ data, int* __restrict__ bsums, int n) {
    __shared__ int tmp[256];
    int idx = blockIdx.x * 256 + threadIdx.x;
    int v = (idx < n) ? data[idx] : 0;
    tmp[threadIdx.x] = v;
    __syncthreads();
    for (int o = 1; o < 256; o <<= 1) {
        int t = (threadIdx.x >= o) ? tmp[threadIdx.x - o] : 0;
        __syncthreads();
        tmp[threadIdx.x] += t;
        __syncthreads();
    }
    if (idx < n) data[idx] = tmp[threadIdx.x];
    if (threadIdx.x == 255) bsums[blockIdx.x] = tmp[255];
}

__global__ __launch_bounds__(256) void scan2_kernel(int* __restrict__ bsums, int nb) {
    __shared__ int tmp[256];
    int t = threadIdx.x;
    int v = (t < nb) ? bsums[t] : 0;
    tmp[t] = v;
    __syncthreads();
    for (int o = 1; o < 256; o <<= 1) {
        int u = (t >= o) ? tmp[t - o] : 0;
        __syncthreads();
        tmp[t] += u;
        __syncthreads();
    }
    if (t < nb) bsums[t] = tmp[t] - v;  // exclusive block offsets
}

__global__ __launch_bounds__(256) void scan3_kernel(int* __restrict__ data, const int* __restrict__ bsums, int n) {
    int idx = blockIdx.x * 256 + threadIdx.x;
    if (idx < n) data[idx] += bsums[blockIdx.x];
}

__global__ __launch_bounds__(256) void fill_kernel(const int* __restrict__ src, const int* __restrict__ dst,
                                                   const int* __restrict__ rowptr, int* __restrict__ cursor,
                                                   int* __restrict__ col) {
    int e = blockIdx.x * 256 + threadIdx.x;
    if (e < N_EDGES) {
        int d = dst[e];
        int p = atomicAdd(&cursor[d], 1);
        col[rowptr[d] + p] = src[e];
    }
}

// ---------------- batched weight transpose fp32 [K][N] -> fp16 [N][K] (all 5 in one dispatch) ----------------
__global__ __launch_bounds__(256) void transw_all(const float* __restrict__ Wa, f16* __restrict__ Ta,
                                                  const float* __restrict__ Wb, f16* __restrict__ Tb,
                                                  const float* __restrict__ Wc, f16* __restrict__ Tc,
                                                  const float* __restrict__ Wd, f16* __restrict__ Td,
                                                  const float* __restrict__ We, f16* __restrict__ Te) {
    const float* W; f16* T; int N, K;
    switch (blockIdx.z) {
        case 0: W = Wa; T = Ta; N = HID;   K = F_IN; break;
        case 1: W = Wb; T = Tb; N = HID;   K = F_IN; break;
        case 2: W = Wc; T = Tc; N = HID;   K = HID;  break;
        case 3: W = Wd; T = Td; N = HID;   K = HID;  break;
        default:W = We; T = Te; N = F_MID; K = HID;  break;
    }
    int n = blockIdx.x * 256 + threadIdx.x;
    int k0 = blockIdx.y * 8;
    if (n >= N || k0 >= K) return;
    f16x8 o;
#pragma unroll
    for (int j = 0; j < 8; j++) o[j] = (f16)W[(size_t)(k0 + j) * N + n];
    *(f16x8*)(T + (size_t)n * K + k0) = o;
}

// ---------------- x fp32 -> fp16 [50000,256] ----------------
__global__ __launch_bounds__(256) void convx_kernel(const float* __restrict__ x, f16* __restrict__ xh) {
    int idx = blockIdx.x * 256 + threadIdx.x;  // 50000*64 float4 units
    float4 v = ((const float4*)x)[idx];
    f16x4 o;
    o[0] = (f16)v.x; o[1] = (f16)v.y; o[2] = (f16)v.z; o[3] = (f16)v.w;
    *(f16x4*)(xh + (size_t)idx * 4) = o;
}

// ---------------- mean aggregation, layer 1 (gathers fp16 xh: half the bytes of fp32 x) ----------------
__global__ __launch_bounds__(256) void agg1_kernel(const f16* __restrict__ xh, const int* __restrict__ rowptr,
                                                   const int* __restrict__ col, f16* __restrict__ agg1h) {
    __shared__ float part[3][64][5];
    const int node = blockIdx.x;
    const int g = threadIdx.x >> 6;
    const int t = threadIdx.x & 63;
    const int beg = rowptr[node], end = rowptr[node + 1];
    float a0 = 0.f, a1 = 0.f, a2 = 0.f, a3 = 0.f;
    for (int e = beg + g; e < end; e += 4) {
        f16x4 v = *(const f16x4*)(xh + (size_t)col[e] * F_IN + t * 4);
        a0 += (float)v[0]; a1 += (float)v[1]; a2 += (float)v[2]; a3 += (float)v[3];
    }
    if (g > 0) {
        part[g - 1][t][0] = a0; part[g - 1][t][1] = a1;
        part[g - 1][t][2] = a2; part[g - 1][t][3] = a3;
    }
    __syncthreads();
    if (g == 0) {
#pragma unroll
        for (int p = 0; p < 3; p++) {
            a0 += part[p][t][0]; a1 += part[p][t][1];
            a2 += part[p][t][2]; a3 += part[p][t][3];
        }
        int deg = end - beg;
        float inv = 1.f / (float)(deg > 1 ? deg : 1);
        f16x4 o;
        o[0] = (f16)(a0 * inv); o[1] = (f16)(a1 * inv);
        o[2] = (f16)(a2 * inv); o[3] = (f16)(a3 * inv);
        *(f16x4*)(agg1h + (size_t)node * F_IN + t * 4) = o;
    }
}

// ---------------- mean aggregation, layer 2 ----------------
__global__ __launch_bounds__(256) void agg2_kernel(const f16* __restrict__ h1, const int* __restrict__ rowptr,
                                                   const int* __restrict__ col, f16* __restrict__ aggbuf,
                                                   int m_base) {
    __shared__ float part[128][9];
    const int node = m_base + blockIdx.x;
    const int g = threadIdx.x >> 7;
    const int t = threadIdx.x & 127;
    const int beg = rowptr[node], end = rowptr[node + 1];
    float a[8], b[8];
#pragma unroll
    for (int j = 0; j < 8; j++) { a[j] = 0.f; b[j] = 0.f; }
    int e = beg + g;
    for (; e + 2 < end; e += 4) {
        int c0 = col[e], c1 = col[e + 2];
        f16x8 v0 = *(const f16x8*)(h1 + (size_t)c0 * HID + t * 8);
        f16x8 v1 = *(const f16x8*)(h1 + (size_t)c1 * HID + t * 8);
#pragma unroll
        for (int j = 0; j < 8; j++) { a[j] += (float)v0[j]; b[j] += (float)v1[j]; }
    }
    if (e < end) {
        f16x8 v0 = *(const f16x8*)(h1 + (size_t)col[e] * HID + t * 8);
#pragma unroll
        for (int j = 0; j < 8; j++) a[j] += (float)v0[j];
    }
#pragma unroll
    for (int j = 0; j < 8; j++) a[j] += b[j];
    if (g == 1) {
#pragma unroll
        for (int j = 0; j < 8; j++) part[t][j] = a[j];
    }
    __syncthreads();
    if (g == 0) {
#pragma unroll
        for (int j = 0; j < 8; j++) a[j] += part[t][j];
        int deg = end - beg;
        float inv = 1.f / (float)(deg > 1 ? deg : 1);
        f16x8 o;
#pragma unroll
        for (int j = 0; j < 8; j++) o[j] = (f16)(a[j] * inv);
        *(f16x8*)(aggbuf + (size_t)blockIdx.x * HID + t * 8) = o;
    }
}

// ---------------- two-source MFMA GEMM v6: 192x128 tile on 512 threads (8 waves), BK=32 dbuf ----------------
// Round-9 model: occupancy-starved latency (96 acc-AGPR/lane -> 2 blocks/CU). Re-sharding the same
// tile over 8 waves (wave tile 48x64, acc=48 AGPR) doubles resident waves -> 16/CU. LDS & XOR swizzle
// unchanged (wm=48w ≡ 0 mod 8 keeps reader key (r16>>1)&3; conflicts stayed 0 in r6-r9).
// A staged in 1.5 passes (waves 0-3 stage rows 128..191). One barrier/iter, stage(t+1) in flight
// during compute(t).
__global__ __launch_bounds__(512, 4) void gemm2_f16(const f16* __restrict__ A0, const f16* __restrict__ B0, int K0,
                                                    const f16* __restrict__ A1, const f16* __restrict__ B1, int K1,
                                                    f16* __restrict__ C, const float* __restrict__ bias,
                                                    float* __restrict__ statsScratch, int M, int N) {
    __shared__ __align__(16) f16 As[2][6144];  // 192 rows x 32, 2 x 12 KB
    __shared__ __align__(16) f16 Bs[2][4096];  // 128 rows x 32, 2 x 8 KB
    const int tid = threadIdx.x;
    const int wave = tid >> 6, lane = tid & 63;
    const int tiles = (M + 191) / 192;
    const int ls = (N >= 1024) ? 3 : 2;
    const int mt = (((int)blockIdx.y) >> ls) * 8 + (int)blockIdx.x;
    if (mt >= tiles) return;
    const int m0 = mt * 192;
    const int n0 = (((int)blockIdx.y) & ((1 << ls) - 1)) << 7;
    const int wm = (wave >> 1) * 48, wn = (wave & 1) << 6;
    const int q = lane >> 4, r16 = lane & 15;

    f32x4 acc[3][4];
#pragma unroll
    for (int i = 0; i < 3; i++)
#pragma unroll
        for (int j = 0; j < 4; j++) acc[i][j] = (f32x4){0.f, 0.f, 0.f, 0.f};

    const int sr = tid >> 2;                                   // 0..127
    const int kc = ((tid & 3) ^ ((tid >> 3) & 3)) * 8;         // XOR-swizzled k-offset (f16)
    int arow1 = m0 + sr;        if (arow1 >= M) arow1 = M - 1;
    int arow2 = m0 + 128 + sr;  if (arow2 >= M) arow2 = M - 1;  // used by tid<256 (rows 128..191)

    const int T0 = K0 / 32;
    const int T = T0 + K1 / 32;

#define STAGE(t, bi)                                                                     \
    {                                                                                    \
        const f16* Ab; const f16* Bb; int kk, KK;                                        \
        if ((t) < T0) { Ab = A0; Bb = B0; kk = (t) * 32;        KK = K0; }               \
        else          { Ab = A1; Bb = B1; kk = ((t) - T0) * 32; KK = K1; }               \
        async_load16(Ab + (size_t)arow1 * KK + kc + kk, &As[bi][wave * 512]);            \
        if (tid < 256)                                                                   \
            async_load16(Ab + (size_t)arow2 * KK + kc + kk, &As[bi][4096 + wave * 512]); \
        async_load16(Bb + (size_t)(n0 + sr) * KK + kc + kk, &Bs[bi][wave * 512]);        \
    }

    STAGE(0, 0);
    const int cb = (q ^ ((r16 >> 1) & 3)) * 8;
    for (int t = 0; t < T; ++t) {
        const int bi = t & 1;
        __syncthreads();                       // drains stage(t) only (t+1 not yet issued)
        if (t + 1 < T) STAGE(t + 1, bi ^ 1);   // flies during compute below
        f16x8 af[3], bfr[4];
#pragma unroll
        for (int i = 0; i < 3; i++)
            af[i] = *(const f16x8*)(&As[bi][(wm + i * 16 + r16) * 32 + cb]);
#pragma unroll
        for (int j = 0; j < 4; j++)
            bfr[j] = *(const f16x8*)(&Bs[bi][(wn + j * 16 + r16) * 32 + cb]);
#pragma unroll
        for (int i = 0; i < 3; i++)
#pragma unroll
            for (int j = 0; j < 4; j++)
                acc[i][j] = __builtin_amdgcn_mfma_f32_16x16x32_f16(af[i], bfr[j], acc[i][j], 0, 0, 0);
    }
#undef STAGE

#pragma unroll
    for (int i = 0; i < 3; i++) {
#pragma unroll
        for (int rr = 0; rr < 4; rr++) {
            int gr = m0 + wm + i * 16 + q * 4 + rr;  // D row = quad*4 + reg
            if (gr < M) {
#pragma unroll
                for (int j = 0; j < 4; j++) {
                    int gc = n0 + wn + j * 16 + r16;  // D col = lane&15
                    float v = acc[i][j][rr];
                    if (bias) {
                        v += bias[gc];
                        v = v > 0.f ? v : 0.f;
                    }
                    C[(size_t)gr * N + gc] = (f16)v;
                }
            }
        }
    }

    if (statsScratch) {
        __syncthreads();  // all waves done reading As before aliasing it
        float* ps = (float*)As;        // 512 floats
        float* pq = (float*)As + 512;  // 512 floats
#pragma unroll
        for (int j = 0; j < 4; j++) {
            float a = 0.f, b = 0.f;
#pragma unroll
            for (int i = 0; i < 3; i++)
#pragma unroll
                for (int rr = 0; rr < 4; rr++) {
                    int gr = m0 + wm + i * 16 + q * 4 + rr;
                    if (gr < M) { float v = acc[i][j][rr]; a += v; b += v * v; }
                }
            a += __shfl_xor(a, 16); a += __shfl_xor(a, 32);
            b += __shfl_xor(b, 16); b += __shfl_xor(b, 32);
            if (q == 0) { ps[wave * 64 + j * 16 + r16] = a; pq[wave * 64 + j * 16 + r16] = b; }
        }
        __syncthreads();
        if (tid < 128) {
            int ch = tid >> 6;   // n-half: cols 0-63 from even waves, 64-127 from odd waves
            int c63 = tid & 63;
            float S = 0.f, Q = 0.f;
#pragma unroll
            for (int m = 0; m < 4; m++) {
                S += ps[(2 * m + ch) * 64 + c63];
                Q += pq[(2 * m + ch) * 64 + c63];
            }
            statsScratch[(size_t)mt * 2048 + n0 + tid] = S;
            statsScratch[(size_t)mt * 2048 + 1024 + n0 + tid] = Q;
        }
    }
}

// ---------------- BN reduce + coef ----------------
__global__ __launch_bounds__(256) void bnreduce_kernel(const float* __restrict__ scratch, int T,
                                                       const float* __restrict__ g, const float* __restrict__ be,
                                                       float* __restrict__ coef) {
    int c = blockIdx.x * 256 + threadIdx.x;  // [0, 1024)
    float S = 0.f, Q = 0.f;
    for (int t = 0; t < T; ++t) {
        S += scratch[(size_t)t * 2048 + c];
        Q += scratch[(size_t)t * 2048 + 1024 + c];
    }
    float m = S / (float)N_NODES;
    float v = Q / (float)N_NODES - m * m;
    float sc = g[c] * rsqrtf(v + 1e-5f);
    coef[c] = sc;
    coef[HID + c] = be[c] - m * sc;
}

__global__ __launch_bounds__(256) void bnapply_kernel(f16* __restrict__ X, const float* __restrict__ coef) {
    int idx = blockIdx.x * 256 + threadIdx.x;  // M * 128 f16x8 units (N=1024)
    int c8 = idx & 127;
    f16x8 v = *(const f16x8*)(X + (size_t)idx * 8);
    float4 sc0 = ((const float4*)coef)[c8 * 2];
    float4 sc1 = ((const float4*)coef)[c8 * 2 + 1];
    float4 sh0 = ((const float4*)(coef + HID))[c8 * 2];
    float4 sh1 = ((const float4*)(coef + HID))[c8 * 2 + 1];
    float y[8];
    y[0] = (float)v[0] * sc0.x + sh0.x; y[1] = (float)v[1] * sc0.y + sh0.y;
    y[2] = (float)v[2] * sc0.z + sh0.z; y[3] = (float)v[3] * sc0.w + sh0.w;
    y[4] = (float)v[4] * sc1.x + sh1.x; y[5] = (float)v[5] * sc1.y + sh1.y;
    y[6] = (float)v[6] * sc1.z + sh1.z; y[7] = (float)v[7] * sc1.w + sh1.w;
    f16x8 o;
#pragma unroll
    for (int j = 0; j < 8; j++) o[j] = (f16)(y[j] > 0.f ? y[j] : 0.f);
    *(f16x8*)(X + (size_t)idx * 8) = o;
}

// ---------------- final fc: out[50000,10] = h3 @ Wo + bo ----------------
__global__ __launch_bounds__(256) void fcout_kernel(const f16* __restrict__ h3, const float* __restrict__ Wo,
                                                    const float* __restrict__ bo, float* __restrict__ out) {
    __shared__ float wos[F_MID * F_OUT];
    for (int i = threadIdx.x; i < F_MID * F_OUT; i += 256) wos[i] = Wo[i];
    __syncthreads();
    int wave = threadIdx.x >> 6, lane = threadIdx.x & 63;
    int node = blockIdx.x * 4 + wave;
    f16x8 v = *(const f16x8*)(h3 + (size_t)node * F_MID + lane * 8);
    float acc[F_OUT];
#pragma unroll
    for (int o = 0; o < F_OUT; o++) acc[o] = 0.f;
#pragma unroll
    for (int j = 0; j < 8; j++) {
        float a = (float)v[j];
        const float* wr = &wos[(lane * 8 + j) * F_OUT];
#pragma unroll
        for (int o = 0; o < F_OUT; o++) acc[o] += a * wr[o];
    }
#pragma unroll
    for (int o = 0; o < F_OUT; o++) {
#pragma unroll
        for (int s = 32; s > 0; s >>= 1) acc[o] += __shfl_down(acc[o], s);
    }
    if (lane == 0) {
#pragma unroll
        for (int o = 0; o < F_OUT; o++) out[(size_t)node * F_OUT + o] = acc[o] + bo[o];
    }
}

extern "C" void kernel_launch(void* const* d_in, const int* in_sizes, int n_in,
                              void* d_out, int out_size, void* d_ws, size_t ws_size,
                              hipStream_t stream) {
    const float* x   = (const float*)d_in[0];
    const int*   edge= (const int*)d_in[1];
    const float* W1l = (const float*)d_in[2];
    const float* W1r = (const float*)d_in[4];
    const float* g1  = (const float*)d_in[5];
    const float* be1 = (const float*)d_in[6];
    const float* W2l = (const float*)d_in[7];
    const float* W2r = (const float*)d_in[9];
    const float* g2  = (const float*)d_in[10];
    const float* be2 = (const float*)d_in[11];
    const float* Wf  = (const float*)d_in[12];
    const float* bf  = (const float*)d_in[13];
    const float* Wo  = (const float*)d_in[14];
    const float* bo  = (const float*)d_in[15];
    float* out = (float*)d_out;

    // b1, b2 unused: per-column constant shift before training-mode BN is a mathematical no-op.

    char* w = (char*)d_ws;
    size_t off = 0;
    auto alloc = [&](size_t bytes) -> void* {
        void* p = w + off;
        off = (off + bytes + 255) & ~(size_t)255;
        return p;
    };
    int* rowptr = (int*)alloc((size_t)(2 * N_NODES + 1) * 4);
    int* cursor = rowptr + (N_NODES + 1);
    int* col    = (int*)alloc((size_t)N_EDGES * 4);
    int* bsums  = (int*)alloc(4096);
    f16* W1lt   = (f16*)alloc((size_t)HID * F_IN * 2);
    f16* W1rt   = (f16*)alloc((size_t)HID * F_IN * 2);
    f16* W2lt   = (f16*)alloc((size_t)HID * HID * 2);
    f16* W2rt   = (f16*)alloc((size_t)HID * HID * 2);
    f16* Wft    = (f16*)alloc((size_t)F_MID * HID * 2);
    float* coef = (float*)alloc((size_t)2 * HID * 4);
    float* statS= (float*)alloc((size_t)392 * 2048 * 4);  // BN-stats scratch [tiles][2][1024]
    // B1 (102.4 MB): h1pre -> h1; later h3
    f16* B1     = (f16*)alloc((size_t)N_NODES * HID * 2);
    // B2 (102.4 MB): [xh | agg1h] -> h2pre -> h2
    f16* B2     = (f16*)alloc((size_t)N_NODES * HID * 2);
    size_t base_off = off;

    int nc = 0;
    {
        const int cand[3] = {2, 4, 8};  // ws < 315.7 MB (round-2 probe), so nc=1 is infeasible anyway
        for (int i = 0; i < 3; i++) {
            size_t need = ((size_t)(N_NODES / cand[i]) * HID * 2 + 255) & ~(size_t)255;
            if (base_off + need <= ws_size) { nc = cand[i]; break; }
        }
    }
    if (nc == 0) {
        probe_kernel<<<(out_size + 255) / 256, 256, 0, stream>>>(out, out_size, (float)(ws_size >> 20));
        return;
    }
    const int chunk = N_NODES / nc;
    f16* aggbuf = (f16*)alloc((size_t)chunk * HID * 2);

    f16* xh    = B2;
    f16* agg1h = B2 + (size_t)N_NODES * F_IN;
    f16* hp    = B1;   // h1pre -> h1
    f16* h2p   = B2;   // h2pre -> h2
    f16* h3    = B1;

    const int* src = edge;
    const int* dst = edge + N_EDGES;

    // CSR build
    zero_i32<<<(2 * N_NODES + 1 + 255) / 256, 256, 0, stream>>>(rowptr, 2 * N_NODES + 1);
    hist_kernel<<<(N_EDGES + 255) / 256, 256, 0, stream>>>(dst, rowptr);
    const int nScan = N_NODES + 1;
    const int nb = (nScan + 255) / 256;
    scan1_kernel<<<nb, 256, 0, stream>>>(rowptr, bsums, nScan);
    scan2_kernel<<<1, 256, 0, stream>>>(bsums, nb);
    scan3_kernel<<<nb, 256, 0, stream>>>(rowptr, bsums, nScan);
    fill_kernel<<<(N_EDGES + 255) / 256, 256, 0, stream>>>(src, dst, rowptr, cursor, col);

    // weights -> fp16 B^T layout (one batched dispatch)
    transw_all<<<dim3(4, 128, 5), 256, 0, stream>>>(W1l, W1lt, W1r, W1rt, W2l, W2lt, W2r, W2rt, Wf, Wft);

    auto gemmGrid = [](int M, int N) {
        int tiles = (M + 191) / 192;
        int nt = N / 128;
        return dim3(8, nt * ((tiles + 7) / 8));
    };

    // layer 1: h1pre = agg1@W1l^T + x@W1r^T (+fused stats)
    convx_kernel<<<(N_NODES * 64) / 256, 256, 0, stream>>>(x, xh);
    agg1_kernel<<<N_NODES, 256, 0, stream>>>(xh, rowptr, col, agg1h);
    gemm2_f16<<<gemmGrid(N_NODES, HID), 512, 0, stream>>>(agg1h, W1lt, F_IN, xh, W1rt, F_IN,
                                                          hp, nullptr, statS, N_NODES, HID);
    const int tiles1 = (N_NODES + 191) / 192;  // 261
    bnreduce_kernel<<<4, 256, 0, stream>>>(statS, tiles1, g1, be1, coef);
    bnapply_kernel<<<(N_NODES * 128) / 256, 256, 0, stream>>>(hp, coef);  // hp := h1

    // layer 2 (M-chunked): h2pre = agg2@W2l^T + h1@W2r^T (+fused stats)
    const int tilesPerChunk = (chunk + 191) / 192;
    for (int c = 0; c < nc; ++c) {
        int m_base = c * chunk;
        agg2_kernel<<<chunk, 256, 0, stream>>>(hp, rowptr, col, aggbuf, m_base);
        gemm2_f16<<<gemmGrid(chunk, HID), 512, 0, stream>>>(
            aggbuf, W2lt, HID, hp + (size_t)m_base * HID, W2rt, HID,
            h2p + (size_t)m_base * HID, nullptr, statS + (size_t)c * tilesPerChunk * 2048, chunk, HID);
    }
    bnreduce_kernel<<<4, 256, 0, stream>>>(statS, nc * tilesPerChunk, g2, be2, coef);
    bnapply_kernel<<<(N_NODES * 128) / 256, 256, 0, stream>>>(h2p, coef);  // h2p := h2

    // head: h3 = relu(h2@Wf^T + bf); out = h3@Wo + bo
    gemm2_f16<<<gemmGrid(N_NODES, F_MID), 512, 0, stream>>>(h2p, Wft, HID, nullptr, nullptr, 0,
                                                            h3, bf, nullptr, N_NODES, F_MID);
    fcout_kernel<<<12500, 256, 0, stream>>>(h3, Wo, bo, out);
}

// Round 11
// 1005.218 us; speedup vs baseline: 1.0995x; 1.0995x over previous
//
#include <hip/hip_runtime.h>
#include <hip/hip_bf16.h>
#include <stdint.h>

#define N_NODES 50000
#define N_EDGES 400000
#define F_IN 256
#define HID 1024
#define F_MID 512
#define F_OUT 10

typedef _Float16 f16;
typedef _Float16 f16x4 __attribute__((ext_vector_type(4)));
typedef _Float16 f16x8 __attribute__((ext_vector_type(8)));
typedef float f32x4 __attribute__((ext_vector_type(4)));

__device__ static inline void async_load16(const void* g, void* l) {
    __builtin_amdgcn_global_load_lds(
        (const __attribute__((address_space(1))) unsigned int*)(uintptr_t)g,
        (__attribute__((address_space(3))) unsigned int*)(uintptr_t)l, 16, 0, 0);
}

// ---------------- utility ----------------
__global__ __launch_bounds__(256) void zero_i32(int* __restrict__ p, int n) {
    int i = blockIdx.x * 256 + threadIdx.x;
    if (i < n) p[i] = 0;
}

__global__ __launch_bounds__(256) void probe_kernel(float* __restrict__ out, int n, float val) {
    int i = blockIdx.x * 256 + threadIdx.x;
    if (i < n) out[i] = (i == 0) ? val : 0.f;
}

// ---------------- CSR build ----------------
__global__ __launch_bounds__(256) void hist_kernel(const int* __restrict__ dst, int* __restrict__ rowptr) {
    int e = blockIdx.x * 256 + threadIdx.x;
    if (e < N_EDGES) atomicAdd(&rowptr[dst[e] + 1], 1);
}

__global__ __launch_bounds__(256) void scan1_kernel(int* __restrict__ data, int* __restrict__ bsums, int n) {
    __shared__ int tmp[256];
    int idx = blockIdx.x * 256 + threadIdx.x;
    int v = (idx < n) ? data[idx] : 0;
    tmp[threadIdx.x] = v;
    __syncthreads();
    for (int o = 1; o < 256; o <<= 1) {
        int t = (threadIdx.x >= o) ? tmp[threadIdx.x - o] : 0;
        __syncthreads();
        tmp[threadIdx.x] += t;
        __syncthreads();
    }
    if (idx < n) data[idx] = tmp[threadIdx.x];
    if (threadIdx.x == 255) bsums[blockIdx.x] = tmp[255];
}

__global__ __launch_bounds__(256) void scan2_kernel(int* __restrict__ bsums, int nb) {
    __shared__ int tmp[256];
    int t = threadIdx.x;
    int v = (t < nb) ? bsums[t] : 0;
    tmp[t] = v;
    __syncthreads();
    for (int o = 1; o < 256; o <<= 1) {
        int u = (t >= o) ? tmp[t - o] : 0;
        __syncthreads();
        tmp[t] += u;
        __syncthreads();
    }
    if (t < nb) bsums[t] = tmp[t] - v;  // exclusive block offsets
}

__global__ __launch_bounds__(256) void scan3_kernel(int* __restrict__ data, const int* __restrict__ bsums, int n) {
    int idx = blockIdx.x * 256 + threadIdx.x;
    if (idx < n) data[idx] += bsums[blockIdx.x];
}

__global__ __launch_bounds__(256) void fill_kernel(const int* __restrict__ src, const int* __restrict__ dst,
                                                   const int* __restrict__ rowptr, int* __restrict__ cursor,
                                                   int* __restrict__ col) {
    int e = blockIdx.x * 256 + threadIdx.x;
    if (e < N_EDGES) {
        int d = dst[e];
        int p = atomicAdd(&cursor[d], 1);
        col[rowptr[d] + p] = src[e];
    }
}

// ---------------- batched weight transpose fp32 [K][N] -> fp16 [N][K] (all 5 in one dispatch) ----------------
__global__ __launch_bounds__(256) void transw_all(const float* __restrict__ Wa, f16* __restrict__ Ta,
                                                  const float* __restrict__ Wb, f16* __restrict__ Tb,
                                                  const float* __restrict__ Wc, f16* __restrict__ Tc,
                                                  const float* __restrict__ Wd, f16* __restrict__ Td,
                                                  const float* __restrict__ We, f16* __restrict__ Te) {
    const float* W; f16* T; int N, K;
    switch (blockIdx.z) {
        case 0: W = Wa; T = Ta; N = HID;   K = F_IN; break;
        case 1: W = Wb; T = Tb; N = HID;   K = F_IN; break;
        case 2: W = Wc; T = Tc; N = HID;   K = HID;  break;
        case 3: W = Wd; T = Td; N = HID;   K = HID;  break;
        default:W = We; T = Te; N = F_MID; K = HID;  break;
    }
    int n = blockIdx.x * 256 + threadIdx.x;
    int k0 = blockIdx.y * 8;
    if (n >= N || k0 >= K) return;
    f16x8 o;
#pragma unroll
    for (int j = 0; j < 8; j++) o[j] = (f16)W[(size_t)(k0 + j) * N + n];
    *(f16x8*)(T + (size_t)n * K + k0) = o;
}

// ---------------- x fp32 -> fp16 [50000,256] ----------------
__global__ __launch_bounds__(256) void convx_kernel(const float* __restrict__ x, f16* __restrict__ xh) {
    int idx = blockIdx.x * 256 + threadIdx.x;  // 50000*64 float4 units
    float4 v = ((const float4*)x)[idx];
    f16x4 o;
    o[0] = (f16)v.x; o[1] = (f16)v.y; o[2] = (f16)v.z; o[3] = (f16)v.w;
    *(f16x4*)(xh + (size_t)idx * 4) = o;
}

// ---------------- mean aggregation, layer 1 v2: barrier-free ----------------
// 4 groups x 64 lanes; each group owns one node (lane covers full row: 64 x f16x4 = 256 cols).
// 4-way edge unroll -> up to 16 gather rows in flight per block; no LDS, no barrier.
__global__ __launch_bounds__(256) void agg1_kernel(const f16* __restrict__ xh, const int* __restrict__ rowptr,
                                                   const int* __restrict__ col, f16* __restrict__ agg1h) {
    const int node = blockIdx.x * 4 + (threadIdx.x >> 6);
    const int t = threadIdx.x & 63;
    const int beg = rowptr[node], end = rowptr[node + 1];
    float a0 = 0.f, a1 = 0.f, a2 = 0.f, a3 = 0.f;
    int e = beg;
    for (; e + 3 < end; e += 4) {
        int c0 = col[e], c1 = col[e + 1], c2 = col[e + 2], c3 = col[e + 3];
        f16x4 v0 = *(const f16x4*)(xh + (size_t)c0 * F_IN + t * 4);
        f16x4 v1 = *(const f16x4*)(xh + (size_t)c1 * F_IN + t * 4);
        f16x4 v2 = *(const f16x4*)(xh + (size_t)c2 * F_IN + t * 4);
        f16x4 v3 = *(const f16x4*)(xh + (size_t)c3 * F_IN + t * 4);
        a0 += (float)v0[0] + (float)v1[0] + (float)v2[0] + (float)v3[0];
        a1 += (float)v0[1] + (float)v1[1] + (float)v2[1] + (float)v3[1];
        a2 += (float)v0[2] + (float)v1[2] + (float)v2[2] + (float)v3[2];
        a3 += (float)v0[3] + (float)v1[3] + (float)v2[3] + (float)v3[3];
    }
    for (; e < end; ++e) {
        f16x4 v = *(const f16x4*)(xh + (size_t)col[e] * F_IN + t * 4);
        a0 += (float)v[0]; a1 += (float)v[1]; a2 += (float)v[2]; a3 += (float)v[3];
    }
    int deg = end - beg;
    float inv = 1.f / (float)(deg > 1 ? deg : 1);
    f16x4 o;
    o[0] = (f16)(a0 * inv); o[1] = (f16)(a1 * inv);
    o[2] = (f16)(a2 * inv); o[3] = (f16)(a3 * inv);
    *(f16x4*)(agg1h + (size_t)node * F_IN + t * 4) = o;
}

// ---------------- mean aggregation, layer 2 v2: barrier-free ----------------
// 2 groups x 128 lanes; each group owns one node (lane covers full row: 128 x f16x8 = 1024 cols).
// 4-way edge unroll -> up to 8 gather rows in flight per block; no LDS, no barrier.
__global__ __launch_bounds__(256) void agg2_kernel(const f16* __restrict__ h1, const int* __restrict__ rowptr,
                                                   const int* __restrict__ col, f16* __restrict__ aggbuf,
                                                   int m_base) {
    const int local = blockIdx.x * 2 + (threadIdx.x >> 7);
    const int node = m_base + local;
    const int t = threadIdx.x & 127;
    const int beg = rowptr[node], end = rowptr[node + 1];
    float a[8];
#pragma unroll
    for (int j = 0; j < 8; j++) a[j] = 0.f;
    int e = beg;
    for (; e + 3 < end; e += 4) {
        int c0 = col[e], c1 = col[e + 1], c2 = col[e + 2], c3 = col[e + 3];
        f16x8 v0 = *(const f16x8*)(h1 + (size_t)c0 * HID + t * 8);
        f16x8 v1 = *(const f16x8*)(h1 + (size_t)c1 * HID + t * 8);
        f16x8 v2 = *(const f16x8*)(h1 + (size_t)c2 * HID + t * 8);
        f16x8 v3 = *(const f16x8*)(h1 + (size_t)c3 * HID + t * 8);
#pragma unroll
        for (int j = 0; j < 8; j++)
            a[j] += (float)v0[j] + (float)v1[j] + (float)v2[j] + (float)v3[j];
    }
    for (; e < end; ++e) {
        f16x8 v = *(const f16x8*)(h1 + (size_t)col[e] * HID + t * 8);
#pragma unroll
        for (int j = 0; j < 8; j++) a[j] += (float)v[j];
    }
    int deg = end - beg;
    float inv = 1.f / (float)(deg > 1 ? deg : 1);
    f16x8 o;
#pragma unroll
    for (int j = 0; j < 8; j++) o[j] = (f16)(a[j] * inv);
    *(f16x8*)(aggbuf + (size_t)local * HID + t * 8) = o;
}

// ---------------- two-source MFMA GEMM (round-9 config): 192x128 tile, 4 waves, BK=32 dbuf ----------------
// LDS-read-BW-bound at ~80% of 85 B/cyc ceiling (r10 analysis); 96x64 wave tile = 38.4 FLOP/LDS-byte
// is the best shard found (8-wave 48x64 = 27.4 regressed). XOR swizzle: conflicts = 0 (r6-r10).
__global__ __launch_bounds__(256, 2) void gemm2_f16(const f16* __restrict__ A0, const f16* __restrict__ B0, int K0,
                                                    const f16* __restrict__ A1, const f16* __restrict__ B1, int K1,
                                                    f16* __restrict__ C, const float* __restrict__ bias,
                                                    float* __restrict__ statsScratch, int M, int N) {
    __shared__ __align__(16) f16 As[2][192 * 32];  // 2 x 12 KB
    __shared__ __align__(16) f16 Bs[2][128 * 32];  // 2 x 8 KB
    const int tid = threadIdx.x;
    const int wave = tid >> 6, lane = tid & 63;
    const int tiles = (M + 191) / 192;
    const int ls = (N >= 1024) ? 3 : 2;
    const int mt = (((int)blockIdx.y) >> ls) * 8 + (int)blockIdx.x;
    if (mt >= tiles) return;
    const int m0 = mt * 192;
    const int n0 = (((int)blockIdx.y) & ((1 << ls) - 1)) << 7;
    const int wm = (wave >> 1) * 96, wn = (wave & 1) << 6;
    const int q = lane >> 4, r16 = lane & 15;

    f32x4 acc[6][4];
#pragma unroll
    for (int i = 0; i < 6; i++)
#pragma unroll
        for (int j = 0; j < 4; j++) acc[i][j] = (f32x4){0.f, 0.f, 0.f, 0.f};

    const int sr = tid >> 2;                              // staged row within 64-row round
    const int kchunk = ((tid & 3) ^ ((sr >> 1) & 3)) * 8; // XOR-swizzled k-offset (f16 elems)
    int arow[3];
#pragma unroll
    for (int j = 0; j < 3; j++) { int r = m0 + sr + 64 * j; arow[j] = (r < M) ? r : (M - 1); }

    const int T0 = K0 / 32;
    const int T = T0 + K1 / 32;

#define STAGE(t, bi)                                                                         \
    {                                                                                        \
        const f16* Ab; const f16* Bb; int kk, KK;                                            \
        if ((t) < T0) { Ab = A0; Bb = B0; kk = (t) * 32;        KK = K0; }                   \
        else          { Ab = A1; Bb = B1; kk = ((t) - T0) * 32; KK = K1; }                   \
        _Pragma("unroll")                                                                    \
        for (int j = 0; j < 3; j++)                                                          \
            async_load16(Ab + (size_t)arow[j] * KK + kchunk + kk,                            \
                         &As[bi][j * 2048 + wave * 512]);                                    \
        _Pragma("unroll")                                                                    \
        for (int j = 0; j < 2; j++)                                                          \
            async_load16(Bb + (size_t)(n0 + sr + 64 * j) * KK + kchunk + kk,                 \
                         &Bs[bi][j * 2048 + wave * 512]);                                    \
    }

    STAGE(0, 0);
    const int cb = (q ^ ((r16 >> 1) & 3)) * 8;
    for (int t = 0; t < T; ++t) {
        const int bi = t & 1;
        __syncthreads();                       // drains stage(t); stage(t+1) not yet issued
        if (t + 1 < T) STAGE(t + 1, bi ^ 1);   // flies during compute below
        f16x8 af[6], bfr[4];
#pragma unroll
        for (int i = 0; i < 6; i++)
            af[i] = *(const f16x8*)(&As[bi][(wm + i * 16 + r16) * 32 + cb]);
#pragma unroll
        for (int j = 0; j < 4; j++)
            bfr[j] = *(const f16x8*)(&Bs[bi][(wn + j * 16 + r16) * 32 + cb]);
#pragma unroll
        for (int i = 0; i < 6; i++)
#pragma unroll
            for (int j = 0; j < 4; j++)
                acc[i][j] = __builtin_amdgcn_mfma_f32_16x16x32_f16(af[i], bfr[j], acc[i][j], 0, 0, 0);
    }
#undef STAGE

#pragma unroll
    for (int i = 0; i < 6; i++) {
#pragma unroll
        for (int rr = 0; rr < 4; rr++) {
            int gr = m0 + wm + i * 16 + q * 4 + rr;  // D row = quad*4 + reg
            if (gr < M) {
#pragma unroll
                for (int j = 0; j < 4; j++) {
                    int gc = n0 + wn + j * 16 + r16;  // D col = lane&15
                    float v = acc[i][j][rr];
                    if (bias) {
                        v += bias[gc];
                        v = v > 0.f ? v : 0.f;
                    }
                    C[(size_t)gr * N + gc] = (f16)v;
                }
            }
        }
    }

    if (statsScratch) {
        __syncthreads();  // all waves done reading As before aliasing it
        float* ps = (float*)As;        // 256 floats (LDS reuse)
        float* pq = (float*)As + 256;
#pragma unroll
        for (int j = 0; j < 4; j++) {
            float a = 0.f, b = 0.f;
#pragma unroll
            for (int i = 0; i < 6; i++)
#pragma unroll
                for (int rr = 0; rr < 4; rr++) {
                    int gr = m0 + wm + i * 16 + q * 4 + rr;
                    if (gr < M) { float v = acc[i][j][rr]; a += v; b += v * v; }
                }
            a += __shfl_xor(a, 16); a += __shfl_xor(a, 32);
            b += __shfl_xor(b, 16); b += __shfl_xor(b, 32);
            if (q == 0) { ps[wave * 64 + j * 16 + r16] = a; pq[wave * 64 + j * 16 + r16] = b; }
        }
        __syncthreads();
        if (tid < 128) {
            int cc = tid & 63;
            int w0 = (tid < 64) ? 0 : 1;  // cols 0-63: waves 0&2; 64-127: waves 1&3
            float S = ps[w0 * 64 + cc] + ps[(w0 + 2) * 64 + cc];
            float Q = pq[w0 * 64 + cc] + pq[(w0 + 2) * 64 + cc];
            statsScratch[(size_t)mt * 2048 + n0 + tid] = S;
            statsScratch[(size_t)mt * 2048 + 1024 + n0 + tid] = Q;
        }
    }
}

// ---------------- BN reduce + coef ----------------
__global__ __launch_bounds__(256) void bnreduce_kernel(const float* __restrict__ scratch, int T,
                                                       const float* __restrict__ g, const float* __restrict__ be,
                                                       float* __restrict__ coef) {
    int c = blockIdx.x * 256 + threadIdx.x;  // [0, 1024)
    float S = 0.f, Q = 0.f;
    for (int t = 0; t < T; ++t) {
        S += scratch[(size_t)t * 2048 + c];
        Q += scratch[(size_t)t * 2048 + 1024 + c];
    }
    float m = S / (float)N_NODES;
    float v = Q / (float)N_NODES - m * m;
    float sc = g[c] * rsqrtf(v + 1e-5f);
    coef[c] = sc;
    coef[HID + c] = be[c] - m * sc;
}

__global__ __launch_bounds__(256) void bnapply_kernel(f16* __restrict__ X, const float* __restrict__ coef) {
    int idx = blockIdx.x * 256 + threadIdx.x;  // M * 128 f16x8 units (N=1024)
    int c8 = idx & 127;
    f16x8 v = *(const f16x8*)(X + (size_t)idx * 8);
    float4 sc0 = ((const float4*)coef)[c8 * 2];
    float4 sc1 = ((const float4*)coef)[c8 * 2 + 1];
    float4 sh0 = ((const float4*)(coef + HID))[c8 * 2];
    float4 sh1 = ((const float4*)(coef + HID))[c8 * 2 + 1];
    float y[8];
    y[0] = (float)v[0] * sc0.x + sh0.x; y[1] = (float)v[1] * sc0.y + sh0.y;
    y[2] = (float)v[2] * sc0.z + sh0.z; y[3] = (float)v[3] * sc0.w + sh0.w;
    y[4] = (float)v[4] * sc1.x + sh1.x; y[5] = (float)v[5] * sc1.y + sh1.y;
    y[6] = (float)v[6] * sc1.z + sh1.z; y[7] = (float)v[7] * sc1.w + sh1.w;
    f16x8 o;
#pragma unroll
    for (int j = 0; j < 8; j++) o[j] = (f16)(y[j] > 0.f ? y[j] : 0.f);
    *(f16x8*)(X + (size_t)idx * 8) = o;
}

// ---------------- final fc: out[50000,10] = h3 @ Wo + bo ----------------
__global__ __launch_bounds__(256) void fcout_kernel(const f16* __restrict__ h3, const float* __restrict__ Wo,
                                                    const float* __restrict__ bo, float* __restrict__ out) {
    __shared__ float wos[F_MID * F_OUT];
    for (int i = threadIdx.x; i < F_MID * F_OUT; i += 256) wos[i] = Wo[i];
    __syncthreads();
    int wave = threadIdx.x >> 6, lane = threadIdx.x & 63;
    int node = blockIdx.x * 4 + wave;
    f16x8 v = *(const f16x8*)(h3 + (size_t)node * F_MID + lane * 8);
    float acc[F_OUT];
#pragma unroll
    for (int o = 0; o < F_OUT; o++) acc[o] = 0.f;
#pragma unroll
    for (int j = 0; j < 8; j++) {
        float a = (float)v[j];
        const float* wr = &wos[(lane * 8 + j) * F_OUT];
#pragma unroll
        for (int o = 0; o < F_OUT; o++) acc[o] += a * wr[o];
    }
#pragma unroll
    for (int o = 0; o < F_OUT; o++) {
#pragma unroll
        for (int s = 32; s > 0; s >>= 1) acc[o] += __shfl_down(acc[o], s);
    }
    if (lane == 0) {
#pragma unroll
        for (int o = 0; o < F_OUT; o++) out[(size_t)node * F_OUT + o] = acc[o] + bo[o];
    }
}

extern "C" void kernel_launch(void* const* d_in, const int* in_sizes, int n_in,
                              void* d_out, int out_size, void* d_ws, size_t ws_size,
                              hipStream_t stream) {
    const float* x   = (const float*)d_in[0];
    const int*   edge= (const int*)d_in[1];
    const float* W1l = (const float*)d_in[2];
    const float* W1r = (const float*)d_in[4];
    const float* g1  = (const float*)d_in[5];
    const float* be1 = (const float*)d_in[6];
    const float* W2l = (const float*)d_in[7];
    const float* W2r = (const float*)d_in[9];
    const float* g2  = (const float*)d_in[10];
    const float* be2 = (const float*)d_in[11];
    const float* Wf  = (const float*)d_in[12];
    const float* bf  = (const float*)d_in[13];
    const float* Wo  = (const float*)d_in[14];
    const float* bo  = (const float*)d_in[15];
    float* out = (float*)d_out;

    // b1, b2 unused: per-column constant shift before training-mode BN is a mathematical no-op.

    char* w = (char*)d_ws;
    size_t off = 0;
    auto alloc = [&](size_t bytes) -> void* {
        void* p = w + off;
        off = (off + bytes + 255) & ~(size_t)255;
        return p;
    };
    int* rowptr = (int*)alloc((size_t)(2 * N_NODES + 1) * 4);
    int* cursor = rowptr + (N_NODES + 1);
    int* col    = (int*)alloc((size_t)N_EDGES * 4);
    int* bsums  = (int*)alloc(4096);
    f16* W1lt   = (f16*)alloc((size_t)HID * F_IN * 2);
    f16* W1rt   = (f16*)alloc((size_t)HID * F_IN * 2);
    f16* W2lt   = (f16*)alloc((size_t)HID * HID * 2);
    f16* W2rt   = (f16*)alloc((size_t)HID * HID * 2);
    f16* Wft    = (f16*)alloc((size_t)F_MID * HID * 2);
    float* coef = (float*)alloc((size_t)2 * HID * 4);
    float* statS= (float*)alloc((size_t)392 * 2048 * 4);  // BN-stats scratch [tiles][2][1024]
    // B1 (102.4 MB): h1pre -> h1; later h3
    f16* B1     = (f16*)alloc((size_t)N_NODES * HID * 2);
    // B2 (102.4 MB): [xh | agg1h] -> h2pre -> h2
    f16* B2     = (f16*)alloc((size_t)N_NODES * HID * 2);
    size_t base_off = off;

    int nc = 0;
    {
        const int cand[3] = {2, 4, 8};  // ws < 315.7 MB (round-2 probe), so nc=1 is infeasible
        for (int i = 0; i < 3; i++) {
            size_t need = ((size_t)(N_NODES / cand[i]) * HID * 2 + 255) & ~(size_t)255;
            if (base_off + need <= ws_size) { nc = cand[i]; break; }
        }
    }
    if (nc == 0) {
        probe_kernel<<<(out_size + 255) / 256, 256, 0, stream>>>(out, out_size, (float)(ws_size >> 20));
        return;
    }
    const int chunk = N_NODES / nc;
    f16* aggbuf = (f16*)alloc((size_t)chunk * HID * 2);

    f16* xh    = B2;
    f16* agg1h = B2 + (size_t)N_NODES * F_IN;
    f16* hp    = B1;   // h1pre -> h1
    f16* h2p   = B2;   // h2pre -> h2
    f16* h3    = B1;

    const int* src = edge;
    const int* dst = edge + N_EDGES;

    // CSR build
    zero_i32<<<(2 * N_NODES + 1 + 255) / 256, 256, 0, stream>>>(rowptr, 2 * N_NODES + 1);
    hist_kernel<<<(N_EDGES + 255) / 256, 256, 0, stream>>>(dst, rowptr);
    const int nScan = N_NODES + 1;
    const int nb = (nScan + 255) / 256;
    scan1_kernel<<<nb, 256, 0, stream>>>(rowptr, bsums, nScan);
    scan2_kernel<<<1, 256, 0, stream>>>(bsums, nb);
    scan3_kernel<<<nb, 256, 0, stream>>>(rowptr, bsums, nScan);
    fill_kernel<<<(N_EDGES + 255) / 256, 256, 0, stream>>>(src, dst, rowptr, cursor, col);

    // weights -> fp16 B^T layout (one batched dispatch)
    transw_all<<<dim3(4, 128, 5), 256, 0, stream>>>(W1l, W1lt, W1r, W1rt, W2l, W2lt, W2r, W2rt, Wf, Wft);

    auto gemmGrid = [](int M, int N) {
        int tiles = (M + 191) / 192;
        int nt = N / 128;
        return dim3(8, nt * ((tiles + 7) / 8));
    };

    // layer 1: h1pre = agg1@W1l^T + x@W1r^T (+fused stats)
    convx_kernel<<<(N_NODES * 64) / 256, 256, 0, stream>>>(x, xh);
    agg1_kernel<<<N_NODES / 4, 256, 0, stream>>>(xh, rowptr, col, agg1h);
    gemm2_f16<<<gemmGrid(N_NODES, HID), 256, 0, stream>>>(agg1h, W1lt, F_IN, xh, W1rt, F_IN,
                                                          hp, nullptr, statS, N_NODES, HID);
    const int tiles1 = (N_NODES + 191) / 192;  // 261
    bnreduce_kernel<<<4, 256, 0, stream>>>(statS, tiles1, g1, be1, coef);
    bnapply_kernel<<<(N_NODES * 128) / 256, 256, 0, stream>>>(hp, coef);  // hp := h1

    // layer 2 (M-chunked): h2pre = agg2@W2l^T + h1@W2r^T (+fused stats)
    const int tilesPerChunk = (chunk + 191) / 192;
    for (int c = 0; c < nc; ++c) {
        int m_base = c * chunk;
        agg2_kernel<<<chunk / 2, 256, 0, stream>>>(hp, rowptr, col, aggbuf, m_base);
        gemm2_f16<<<gemmGrid(chunk, HID), 256, 0, stream>>>(
            aggbuf, W2lt, HID, hp + (size_t)m_base * HID, W2rt, HID,
            h2p + (size_t)m_base * HID, nullptr, statS + (size_t)c * tilesPerChunk * 2048, chunk, HID);
    }
    bnreduce_kernel<<<4, 256, 0, stream>>>(statS, nc * tilesPerChunk, g2, be2, coef);
    bnapply_kernel<<<(N_NODES * 128) / 256, 256, 0, stream>>>(h2p, coef);  // h2p := h2

    // head: h3 = relu(h2@Wf^T + bf); out = h3@Wo + bo
    gemm2_f16<<<gemmGrid(N_NODES, F_MID), 256, 0, stream>>>(h2p, Wft, HID, nullptr, nullptr, 0,
                                                            h3, bf, nullptr, N_NODES, F_MID);
    fcout_kernel<<<12500, 256, 0, stream>>>(h3, Wo, bo, out);
}